// Round 1
// baseline (352.398 us; speedup 1.0000x reference)
//
#include <hip/hip_runtime.h>

#define B_  2048
#define N_  64
#define H_  4
#define FI  256
#define FO  256
#define HF  1024   // H*FO

typedef _Float16 f16;
typedef _Float16 f16x8 __attribute__((ext_vector_type(8)));
typedef _Float16 f16x4 __attribute__((ext_vector_type(4)));
typedef float f32x4 __attribute__((ext_vector_type(4)));

#define MFMA16(a,b,c) __builtin_amdgcn_mfma_f32_16x16x32_f16(a, b, c, 0, 0, 0)

// ---------------------------------------------------------------------------
// W prep: W [256][1024] f32 -> f16 MFMA B-fragments in workspace.
// layout: frag[kt(8)][ctg(64)][lane(64)][j(8)]
// element: W[kt*32 + (lane>>4)*8 + j][ctg*16 + (lane&15)]
// ---------------------------------------------------------------------------
__global__ __launch_bounds__(256) void prep_w_kernel(const float* __restrict__ W,
                                                     f16* __restrict__ wfrag) {
    int tid  = blockIdx.x * 256 + threadIdx.x;   // 0..32767
    int lane = tid & 63;
    int ctg  = (tid >> 6) & 63;
    int kt   = tid >> 12;                        // 0..7
    int krow = kt * 32 + (lane >> 4) * 8;
    int col  = ctg * 16 + (lane & 15);
    f16x8 v;
#pragma unroll
    for (int j = 0; j < 8; ++j)
        v[j] = (f16)W[(size_t)(krow + j) * HF + col];
    *((f16x8*)wfrag + tid) = v;
}

// ---------------------------------------------------------------------------
// Fused GAT kernel: 1 block = 1 batch, 4 waves = 4 heads.
// LDS layout (bytes):
//   [0, 32768)        : sA (input f16 [64][256], swizzled) -> later sHT chunk cc=3
//   [32768, 131072)   : sHT chunks cc=0..2 : per (w,cc) 8KB region [64 col][64 j] f16
//   [131072, 132096)  : sCi [4][64] f32
//   [132096, 133120)  : sCj [4][64] f32
//   [133120, 149760)  : sAdj [64][65] f32 (pad 65 vs bank conflicts)
// ---------------------------------------------------------------------------
#define SMEM_BYTES 149760
#define SCI_OFF    131072
#define SCJ_OFF    132096
#define SADJ_OFF   133120

__device__ __forceinline__ unsigned ht_base(int w, int cc) {
    return (cc == 3) ? (unsigned)(w * 8192)
                     : (unsigned)(32768 + (w * 3 + cc) * 8192);
}

__global__ __launch_bounds__(256, 1) void gat_kernel(
    const float* __restrict__ input, const float* __restrict__ adj,
    const f16* __restrict__ wfrag, const float* __restrict__ a_i,
    const float* __restrict__ a_j, const float* __restrict__ bias,
    float* __restrict__ out)
{
    __shared__ unsigned char smem[SMEM_BYTES] __attribute__((aligned(16)));
    float* sCi  = (float*)(smem + SCI_OFF);
    float* sCj  = (float*)(smem + SCJ_OFF);
    float* sAdj = (float*)(smem + SADJ_OFF);

    const int b    = blockIdx.x;
    const int tid  = threadIdx.x;
    const int w    = tid >> 6;      // wave = head
    const int lane = tid & 63;
    const int g    = lane >> 4;
    const int c15  = lane & 15;

    // ---- phase 0: stage input (f32->f16, swizzled) and adj into LDS ----
    {
        const float* inb = input + (size_t)b * (N_ * FI);
#pragma unroll
        for (int c = 0; c < 8; ++c) {
            int idx = tid + 256 * c;          // 0..2047, 8-float chunks
            int row = idx >> 5;               // 32 chunks per row
            int k0  = (idx & 31) << 3;
            const float4* p = (const float4*)(inb + row * FI + k0);
            float4 v0 = p[0], v1 = p[1];
            f16x8 hv;
            hv[0] = (f16)v0.x; hv[1] = (f16)v0.y; hv[2] = (f16)v0.z; hv[3] = (f16)v0.w;
            hv[4] = (f16)v1.x; hv[5] = (f16)v1.y; hv[6] = (f16)v1.z; hv[7] = (f16)v1.w;
            unsigned addr = (unsigned)(row * 512 + k0 * 2) ^ ((unsigned)(row & 7) << 4);
            *(f16x8*)(smem + addr) = hv;
        }
        const float4* adjb = (const float4*)(adj + (size_t)b * (N_ * N_));
#pragma unroll
        for (int c = 0; c < 4; ++c) {
            int idx = tid + 256 * c;          // 0..1023 float4s
            float4 v = adjb[idx];
            int i = idx >> 4;
            int j = (idx & 15) << 2;
            float* dst = sAdj + i * 65 + j;
            dst[0] = v.x; dst[1] = v.y; dst[2] = v.z; dst[3] = v.w;
        }
    }
    __syncthreads();

    // ---- GEMM1: h = input_b @ W[:, head w], with coeff epilogue ----
    float ciP[16], cjP[16];
#pragma unroll
    for (int q = 0; q < 16; ++q) { ciP[q] = 0.f; cjP[q] = 0.f; }

#pragma unroll
    for (int cc = 0; cc < 4; ++cc) {
        f32x4 acc[4][4];
#pragma unroll
        for (int rt = 0; rt < 4; ++rt)
#pragma unroll
            for (int ct = 0; ct < 4; ++ct) {
                f32x4 z = {0.f, 0.f, 0.f, 0.f};
                acc[rt][ct] = z;
            }
#pragma unroll
        for (int kt = 0; kt < 8; ++kt) {
            f16x8 aF[4];
#pragma unroll
            for (int rt = 0; rt < 4; ++rt) {
                int row = rt * 16 + c15;
                unsigned addr = ((unsigned)(row * 512 + (kt * 32 + g * 8) * 2))
                                ^ ((unsigned)(row & 7) << 4);
                aF[rt] = *(const f16x8*)(smem + addr);
            }
            f16x8 bF[4];
#pragma unroll
            for (int ct = 0; ct < 4; ++ct) {
                int ctg = w * 16 + cc * 4 + ct;
                bF[ct] = *((const f16x8*)wfrag + ((kt * 64 + ctg) * 64 + lane));
            }
#pragma unroll
            for (int rt = 0; rt < 4; ++rt)
#pragma unroll
                for (int ct = 0; ct < 4; ++ct)
                    acc[rt][ct] = MFMA16(aF[rt], bF[ct], acc[rt][ct]);
        }
        if (cc == 3) __syncthreads();   // all waves done reading sA before reuse
        unsigned base = ht_base(w, cc);
#pragma unroll
        for (int ct = 0; ct < 4; ++ct) {
            float aIc = a_i[w * FO + (cc * 4 + ct) * 16 + c15];
            float aJc = a_j[w * FO + (cc * 4 + ct) * 16 + c15];
#pragma unroll
            for (int rt = 0; rt < 4; ++rt) {
                f16x4 hv;
#pragma unroll
                for (int r = 0; r < 4; ++r) {
                    float v = acc[rt][ct][r];
                    ciP[rt * 4 + r] += v * aIc;
                    cjP[rt * 4 + r] += v * aJc;
                    hv[r] = (f16)v;
                }
                int col_local = ct * 16 + c15;
                int j0 = rt * 16 + g * 4;
                unsigned addr = base + (((unsigned)(col_local * 128 + j0 * 2))
                                        ^ ((unsigned)(col_local & 7) << 4));
                *(f16x4*)(smem + addr) = hv;   // h transposed: [col][node]
            }
        }
    }

    // ---- coeff reduce across the 16 lanes of each quarter-wave ----
#pragma unroll
    for (int s = 1; s < 16; s <<= 1) {
#pragma unroll
        for (int q = 0; q < 16; ++q) {
            ciP[q] += __shfl_xor(ciP[q], s);
            cjP[q] += __shfl_xor(cjP[q], s);
        }
    }
    if (c15 == 0) {
#pragma unroll
        for (int q = 0; q < 16; ++q) {
            int row = (q >> 2) * 16 + g * 4 + (q & 3);
            sCi[w * 64 + row] = ciP[q];
            sCj[w * 64 + row] = cjP[q];
        }
    }
    // wave-internal LDS write->read: compiler-inserted lgkmcnt orders it.

    // ---- attention: softmax rows, packed straight into A-fragments ----
    f16x8 attnF[4][2];
    float cjv[16];
    {
        const float* cjp = sCj + w * 64;
#pragma unroll
        for (int t = 0; t < 8; ++t) cjv[t]     = cjp[8 * g + t];
#pragma unroll
        for (int t = 0; t < 8; ++t) cjv[8 + t] = cjp[32 + 8 * g + t];
    }
#pragma unroll
    for (int rt = 0; rt < 4; ++rt) {
        int i = rt * 16 + c15;
        float ci = sCi[w * 64 + i];
        float sv[16], av[16];
        float m = -1e30f;
#pragma unroll
        for (int q = 0; q < 16; ++q) {
            int j = (q >> 3) * 32 + 8 * g + (q & 7);
            float adjv = sAdj[i * 65 + j];
            float e = ci + cjv[q];
            e = fmaxf(e, 0.2f * e);          // leaky_relu, slope 0.2
            float s = e * adjv;
            av[q] = adjv;
            sv[q] = s;
            m = fmaxf(m, s);
        }
        m = fmaxf(m, __shfl_xor(m, 16));
        m = fmaxf(m, __shfl_xor(m, 32));
        float sum = 0.f;
#pragma unroll
        for (int q = 0; q < 16; ++q) { float p = __expf(sv[q] - m); sv[q] = p; sum += p; }
        sum += __shfl_xor(sum, 16);
        sum += __shfl_xor(sum, 32);
        float rs = 1.0f / sum;
#pragma unroll
        for (int q = 0; q < 16; ++q) sv[q] = sv[q] * rs * av[q];
#pragma unroll
        for (int jj = 0; jj < 8; ++jj) {
            attnF[rt][0][jj] = (f16)sv[jj];
            attnF[rt][1][jj] = (f16)sv[8 + jj];
        }
    }

    // ---- GEMM2: out = attn @ h, + bias ----
#pragma unroll
    for (int cc = 0; cc < 4; ++cc) {
        f32x4 acc[4][4];
#pragma unroll
        for (int rt = 0; rt < 4; ++rt)
#pragma unroll
            for (int ct = 0; ct < 4; ++ct) {
                f32x4 z = {0.f, 0.f, 0.f, 0.f};
                acc[rt][ct] = z;
            }
        unsigned base = ht_base(w, cc);
#pragma unroll
        for (int kt = 0; kt < 2; ++kt) {
            f16x8 bF[4];
#pragma unroll
            for (int ct = 0; ct < 4; ++ct) {
                int col_local = ct * 16 + c15;
                unsigned addr = base + (((unsigned)(col_local * 128 + (kt * 32 + g * 8) * 2))
                                        ^ ((unsigned)(col_local & 7) << 4));
                bF[ct] = *(const f16x8*)(smem + addr);
            }
#pragma unroll
            for (int rt = 0; rt < 4; ++rt)
#pragma unroll
                for (int ct = 0; ct < 4; ++ct)
                    acc[rt][ct] = MFMA16(attnF[rt][kt], bF[ct], acc[rt][ct]);
        }
#pragma unroll
        for (int ct = 0; ct < 4; ++ct) {
            int colg = w * FO + cc * 64 + ct * 16 + c15;
            float bv = bias[colg];
#pragma unroll
            for (int rt = 0; rt < 4; ++rt) {
#pragma unroll
                for (int r = 0; r < 4; ++r) {
                    int row = rt * 16 + g * 4 + r;
                    out[((size_t)b * N_ + row) * HF + colg] = acc[rt][ct][r] + bv;
                }
            }
        }
    }
}

extern "C" void kernel_launch(void* const* d_in, const int* in_sizes, int n_in,
                              void* d_out, int out_size, void* d_ws, size_t ws_size,
                              hipStream_t stream) {
    const float* input = (const float*)d_in[0];
    const float* adj   = (const float*)d_in[1];
    const float* W     = (const float*)d_in[2];
    const float* a_i   = (const float*)d_in[3];
    const float* a_j   = (const float*)d_in[4];
    const float* bias  = (const float*)d_in[5];
    float* outp  = (float*)d_out;
    f16*   wfrag = (f16*)d_ws;   // 512 KB

    prep_w_kernel<<<128, 256, 0, stream>>>(W, wfrag);
    gat_kernel<<<B_, 256, 0, stream>>>(input, adj, wfrag, a_i, a_j, bias, outp);
}

// Round 2
// 250.387 us; speedup vs baseline: 1.4074x; 1.4074x over previous
//
#include <hip/hip_runtime.h>

#define B_  2048
#define N_  64
#define H_  4
#define FI  256
#define FO  256
#define HF  1024   // H*FO

typedef _Float16 f16;
typedef _Float16 f16x8 __attribute__((ext_vector_type(8)));
typedef _Float16 f16x4 __attribute__((ext_vector_type(4)));
typedef float f32x4 __attribute__((ext_vector_type(4)));

#define MFMA16(a,b,c) __builtin_amdgcn_mfma_f32_16x16x32_f16(a, b, c, 0, 0, 0)

// ---------------------------------------------------------------------------
// W prep: W [256][1024] f32 -> f16 MFMA B-fragments in workspace.
// layout: frag[kt(8)][ctg(64)][lane(64)][j(8)]
// element: W[kt*32 + (lane>>4)*8 + j][ctg*16 + (lane&15)]
// ---------------------------------------------------------------------------
__global__ __launch_bounds__(256) void prep_w_kernel(const float* __restrict__ W,
                                                     f16* __restrict__ wfrag) {
    int tid  = blockIdx.x * 256 + threadIdx.x;   // 0..32767
    int lane = tid & 63;
    int ctg  = (tid >> 6) & 63;
    int kt   = tid >> 12;                        // 0..7
    int krow = kt * 32 + (lane >> 4) * 8;
    int col  = ctg * 16 + (lane & 15);
    f16x8 v;
#pragma unroll
    for (int j = 0; j < 8; ++j)
        v[j] = (f16)W[(size_t)(krow + j) * HF + col];
    *((f16x8*)wfrag + tid) = v;
}

// ---------------------------------------------------------------------------
// Fused GAT kernel: 1 block = 1 batch, 8 waves = 4 heads x 2 half-waves.
//   GEMM1: head w split by col-chunks (hv=0: cc 0,1 ; hv=1: cc 2,3)
//   softmax/GEMM2: head w split by row-tiles (hv=0: rt 0,1 ; hv=1: rt 2,3)
// LDS layout (bytes):
//   [0, 32768)        : sA (input f16 [64][256], swizzled) -> later sHT chunk cc=3
//   [32768, 131072)   : sHT chunks cc=0..2 : per (w,cc) 8KB region [64 col][64 j] f16
//   [131072, 133120)  : sCi2 [4][2][64] f32  (per half-wave partial coeffs)
//   [133120, 135168)  : sCj2 [4][2][64] f32
//   [135168, 151808)  : sAdj [64][65] f32 (pad 65 vs bank conflicts)
// ---------------------------------------------------------------------------
#define SMEM_BYTES 151808
#define SCI_OFF    131072
#define SCJ_OFF    133120
#define SADJ_OFF   135168

__device__ __forceinline__ unsigned ht_base(int w, int cc) {
    return (cc == 3) ? (unsigned)(w * 8192)
                     : (unsigned)(32768 + (w * 3 + cc) * 8192);
}

__global__ __launch_bounds__(512, 2) void gat_kernel(
    const float* __restrict__ input, const float* __restrict__ adj,
    const f16* __restrict__ wfrag, const float* __restrict__ a_i,
    const float* __restrict__ a_j, const float* __restrict__ bias,
    float* __restrict__ out)
{
    __shared__ unsigned char smem[SMEM_BYTES] __attribute__((aligned(16)));
    float* sCi2 = (float*)(smem + SCI_OFF);
    float* sCj2 = (float*)(smem + SCJ_OFF);
    float* sAdj = (float*)(smem + SADJ_OFF);

    const int b    = blockIdx.x;
    const int tid  = threadIdx.x;
    const int wv   = tid >> 6;      // wave 0..7
    const int w    = wv >> 1;       // head
    const int hv   = wv & 1;        // half index within head
    const int lane = tid & 63;
    const int g    = lane >> 4;
    const int c15  = lane & 15;

    // ---- phase 0: stage input (f32->f16, swizzled) and adj into LDS ----
    {
        const float* inb = input + (size_t)b * (N_ * FI);
#pragma unroll
        for (int c = 0; c < 4; ++c) {
            int idx = tid + 512 * c;          // 0..2047, 8-float chunks
            int row = idx >> 5;               // 32 chunks per row
            int k0  = (idx & 31) << 3;
            const float4* p = (const float4*)(inb + row * FI + k0);
            float4 v0 = p[0], v1 = p[1];
            f16x8 hv8;
            hv8[0] = (f16)v0.x; hv8[1] = (f16)v0.y; hv8[2] = (f16)v0.z; hv8[3] = (f16)v0.w;
            hv8[4] = (f16)v1.x; hv8[5] = (f16)v1.y; hv8[6] = (f16)v1.z; hv8[7] = (f16)v1.w;
            unsigned addr = (unsigned)(row * 512 + k0 * 2) ^ ((unsigned)(row & 7) << 4);
            *(f16x8*)(smem + addr) = hv8;
        }
        const float4* adjb = (const float4*)(adj + (size_t)b * (N_ * N_));
#pragma unroll
        for (int c = 0; c < 2; ++c) {
            int idx = tid + 512 * c;          // 0..1023 float4s
            float4 v = adjb[idx];
            int i = idx >> 4;
            int j = (idx & 15) << 2;
            float* dst = sAdj + i * 65 + j;
            dst[0] = v.x; dst[1] = v.y; dst[2] = v.z; dst[3] = v.w;
        }
    }
    __syncthreads();

    // ---- GEMM1: h = input_b @ W[:, head w], cols split across half-waves ----
    float ciP[16], cjP[16];
#pragma unroll
    for (int q = 0; q < 16; ++q) { ciP[q] = 0.f; cjP[q] = 0.f; }

    f32x4 acc[4][4];

    // macro-ish epilogue as a lambda: write h chunk cc + accumulate coeffs
    auto epilogue = [&](int cc) {
        unsigned base = ht_base(w, cc);
#pragma unroll
        for (int ct = 0; ct < 4; ++ct) {
            float aIc = a_i[w * FO + (cc * 4 + ct) * 16 + c15];
            float aJc = a_j[w * FO + (cc * 4 + ct) * 16 + c15];
#pragma unroll
            for (int rt = 0; rt < 4; ++rt) {
                f16x4 hv4;
#pragma unroll
                for (int r = 0; r < 4; ++r) {
                    float v = acc[rt][ct][r];
                    ciP[rt * 4 + r] += v * aIc;
                    cjP[rt * 4 + r] += v * aJc;
                    hv4[r] = (f16)v;
                }
                int col_local = ct * 16 + c15;
                int j0 = rt * 16 + g * 4;
                unsigned addr = base + (((unsigned)(col_local * 128 + j0 * 2))
                                        ^ ((unsigned)(col_local & 7) << 4));
                *(f16x4*)(smem + addr) = hv4;   // h transposed: [col][node]
            }
        }
    };

    auto compute_chunk = [&](int cc) {
#pragma unroll
        for (int rt = 0; rt < 4; ++rt)
#pragma unroll
            for (int ct = 0; ct < 4; ++ct) {
                f32x4 z = {0.f, 0.f, 0.f, 0.f};
                acc[rt][ct] = z;
            }
#pragma unroll
        for (int kt = 0; kt < 8; ++kt) {
            f16x8 aF[4];
#pragma unroll
            for (int rt = 0; rt < 4; ++rt) {
                int row = rt * 16 + c15;
                unsigned addr = ((unsigned)(row * 512 + (kt * 32 + g * 8) * 2))
                                ^ ((unsigned)(row & 7) << 4);
                aF[rt] = *(const f16x8*)(smem + addr);
            }
            f16x8 bF[4];
#pragma unroll
            for (int ct = 0; ct < 4; ++ct) {
                int ctg = w * 16 + cc * 4 + ct;
                bF[ct] = *((const f16x8*)wfrag + ((kt * 64 + ctg) * 64 + lane));
            }
#pragma unroll
            for (int rt = 0; rt < 4; ++rt)
#pragma unroll
                for (int ct = 0; ct < 4; ++ct)
                    acc[rt][ct] = MFMA16(aF[rt], bF[ct], acc[rt][ct]);
        }
    };

    const int cc0 = hv * 2;       // 0 or 2
    const int cc1 = hv * 2 + 1;   // 1 or 3

    compute_chunk(cc0);
    epilogue(cc0);                // cc0 is never 3: safe to write immediately
    compute_chunk(cc1);
    if (hv == 0) epilogue(cc1);   // cc==1: separate region, write now
    __syncthreads();              // ALL waves: sA reads complete
    if (hv == 1) epilogue(cc1);   // cc==3: reuses sA region, write after barrier

    // ---- coeff reduce across the 16 lanes of each quarter-wave ----
#pragma unroll
    for (int s = 1; s < 16; s <<= 1) {
#pragma unroll
        for (int q = 0; q < 16; ++q) {
            ciP[q] += __shfl_xor(ciP[q], s);
            cjP[q] += __shfl_xor(cjP[q], s);
        }
    }
    if (c15 == 0) {
#pragma unroll
        for (int q = 0; q < 16; ++q) {
            int row = (q >> 2) * 16 + g * 4 + (q & 3);
            sCi2[(w * 2 + hv) * 64 + row] = ciP[q];
            sCj2[(w * 2 + hv) * 64 + row] = cjP[q];
        }
    }
    __syncthreads();   // coeffs + all h chunks visible to both half-waves

    // ---- attention: softmax rows (split: hv picks 2 of 4 row-tiles) ----
    f16x8 attnF[2][2];
    float cjv[16];
    {
        const float* cj0 = sCj2 + (w * 2 + 0) * 64;
        const float* cj1 = sCj2 + (w * 2 + 1) * 64;
#pragma unroll
        for (int t = 0; t < 8; ++t) cjv[t]     = cj0[8 * g + t]      + cj1[8 * g + t];
#pragma unroll
        for (int t = 0; t < 8; ++t) cjv[8 + t] = cj0[32 + 8 * g + t] + cj1[32 + 8 * g + t];
    }
    const float* ci0 = sCi2 + (w * 2 + 0) * 64;
    const float* ci1 = sCi2 + (w * 2 + 1) * 64;
#pragma unroll
    for (int rtl = 0; rtl < 2; ++rtl) {
        int rt = hv * 2 + rtl;
        int i = rt * 16 + c15;
        float ci = ci0[i] + ci1[i];
        float sv[16], av[16];
        float m = -1e30f;
#pragma unroll
        for (int q = 0; q < 16; ++q) {
            int j = (q >> 3) * 32 + 8 * g + (q & 7);
            float adjv = sAdj[i * 65 + j];
            float e = ci + cjv[q];
            e = fmaxf(e, 0.2f * e);          // leaky_relu, slope 0.2
            float s = e * adjv;
            av[q] = adjv;
            sv[q] = s;
            m = fmaxf(m, s);
        }
        m = fmaxf(m, __shfl_xor(m, 16));
        m = fmaxf(m, __shfl_xor(m, 32));
        float sum = 0.f;
#pragma unroll
        for (int q = 0; q < 16; ++q) { float p = __expf(sv[q] - m); sv[q] = p; sum += p; }
        sum += __shfl_xor(sum, 16);
        sum += __shfl_xor(sum, 32);
        float rs = 1.0f / sum;
#pragma unroll
        for (int q = 0; q < 16; ++q) sv[q] = sv[q] * rs * av[q];
#pragma unroll
        for (int jj = 0; jj < 8; ++jj) {
            attnF[rtl][0][jj] = (f16)sv[jj];
            attnF[rtl][1][jj] = (f16)sv[8 + jj];
        }
    }

    // ---- GEMM2: out = attn @ h, + bias (rows split across half-waves) ----
#pragma unroll
    for (int cc = 0; cc < 4; ++cc) {
        f32x4 acc2[2][4];
#pragma unroll
        for (int rtl = 0; rtl < 2; ++rtl)
#pragma unroll
            for (int ct = 0; ct < 4; ++ct) {
                f32x4 z = {0.f, 0.f, 0.f, 0.f};
                acc2[rtl][ct] = z;
            }
        unsigned base = ht_base(w, cc);
#pragma unroll
        for (int kt = 0; kt < 2; ++kt) {
            f16x8 bF[4];
#pragma unroll
            for (int ct = 0; ct < 4; ++ct) {
                int col_local = ct * 16 + c15;
                unsigned addr = base + (((unsigned)(col_local * 128 + (kt * 32 + g * 8) * 2))
                                        ^ ((unsigned)(col_local & 7) << 4));
                bF[ct] = *(const f16x8*)(smem + addr);
            }
#pragma unroll
            for (int rtl = 0; rtl < 2; ++rtl)
#pragma unroll
                for (int ct = 0; ct < 4; ++ct)
                    acc2[rtl][ct] = MFMA16(attnF[rtl][kt], bF[ct], acc2[rtl][ct]);
        }
#pragma unroll
        for (int ct = 0; ct < 4; ++ct) {
            int colg = w * FO + cc * 64 + ct * 16 + c15;
            float bv = bias[colg];
#pragma unroll
            for (int rtl = 0; rtl < 2; ++rtl) {
#pragma unroll
                for (int r = 0; r < 4; ++r) {
                    int row = (hv * 2 + rtl) * 16 + g * 4 + r;
                    out[((size_t)b * N_ + row) * HF + colg] = acc2[rtl][ct][r] + bv;
                }
            }
        }
    }
}

extern "C" void kernel_launch(void* const* d_in, const int* in_sizes, int n_in,
                              void* d_out, int out_size, void* d_ws, size_t ws_size,
                              hipStream_t stream) {
    const float* input = (const float*)d_in[0];
    const float* adj   = (const float*)d_in[1];
    const float* W     = (const float*)d_in[2];
    const float* a_i   = (const float*)d_in[3];
    const float* a_j   = (const float*)d_in[4];
    const float* bias  = (const float*)d_in[5];
    float* outp  = (float*)d_out;
    f16*   wfrag = (f16*)d_ws;   // 512 KB

    prep_w_kernel<<<128, 256, 0, stream>>>(W, wfrag);
    gat_kernel<<<B_, 512, 0, stream>>>(input, adj, wfrag, a_i, a_j, bias, outp);
}